// Round 13
// baseline (120.066 us; speedup 1.0000x reference)
//
#include <hip/hip_runtime.h>

// ---------------------------------------------------------------------------
// IncidenceAttention. incidence = (Q·K~^T)*SCALE with K~[d] = K[d] + mw*K[d^32].
// Pipeline: cast -> QKV gemm (8-wave 128^2 tiles, mfma 32x32x16) -> flash attn
//           (r12 structure: 2-deep K, (256,2), setprio clusters - 7-variant
//           plateau at ~55us) -> out gemm (64x128, mfma 32x32x16).
// R13: GEMM inner math 16x16x32 -> 32x32x16 (ubench +15%, half the MFMA
//      instruction count, same LDS traffic). Wave tile 32m x 64n keeps the
//      K-fold partner col n^32 in-wave (acc[nf^1]).
// ---------------------------------------------------------------------------

typedef __attribute__((ext_vector_type(8))) short short8;
typedef __attribute__((ext_vector_type(4))) short s16x4;
typedef __attribute__((ext_vector_type(4))) float f32x4;
typedef __attribute__((ext_vector_type(16))) float f32x16;
typedef __attribute__((ext_vector_type(8))) __bf16 bf16x8;
typedef __attribute__((ext_vector_type(4))) unsigned uint4v;

__device__ __forceinline__ float exp2fa(float x) {
  return __builtin_amdgcn_exp2f(x);  // v_exp_f32: 2^x
}
__device__ __forceinline__ short f2bf(float f) {
  unsigned u = __builtin_bit_cast(unsigned, f);
  u = u + 0x7fffu + ((u >> 16) & 1u);  // RNE
  return (short)(u >> 16);
}
__device__ __forceinline__ f32x16 mfma32(bf16x8 a, bf16x8 b, f32x16 c) {
  return __builtin_amdgcn_mfma_f32_32x32x16_bf16(a, b, c, 0, 0, 0);
}
__device__ __forceinline__ void gload_lds16(const void* g, void* l) {
  __builtin_amdgcn_global_load_lds(
      (const __attribute__((address_space(1))) unsigned int*)g,
      (__attribute__((address_space(3))) unsigned int*)l, 16, 0, 0);
}
__device__ __forceinline__ unsigned pkbf(float a, float b) {
  unsigned r;
  asm("v_cvt_pk_bf16_f32 %0, %1, %2" : "=v"(r) : "v"(a), "v"(b));
  return r;
}
__device__ __forceinline__ void plswap(unsigned& a, unsigned& b) {
  asm volatile("v_permlane32_swap_b32 %0, %1" : "+v"(a), "+v"(b));
}
// pack 8 f32 P values into the PV B-operand fragment (m214 T12 pattern).
__device__ __forceinline__ bf16x8 pack8(float x0, float x1, float x2, float x3,
                                        float x4, float x5, float x6, float x7) {
  unsigned a0 = pkbf(x0, x1), a1 = pkbf(x2, x3);
  unsigned a2 = pkbf(x4, x5), a3 = pkbf(x6, x7);
  plswap(a0, a2);
  plswap(a1, a3);
  uint4v u = {a0, a1, a2, a3};
  return __builtin_bit_cast(bf16x8, u);
}

// ---- merged cast: x (4 chunks) + 4 weight matrices, one launch -------------
__global__ void cast_all_kernel(const float* x, const float* w0, const float* w1,
                                const float* w2, const float* w3, short* xo,
                                short* o0, short* o1, short* o2, short* o3) {
  const float* in; short* out;
  const int r = blockIdx.y;
  size_t off;
  if (r < 4) { in = x; out = xo; off = (size_t)r * 131072; }
  else {
    switch (r) {
      case 4: in = w0; out = o0; break;
      case 5: in = w1; out = o1; break;
      case 6: in = w2; out = o2; break;
      default: in = w3; out = o3; break;
    }
    off = 0;
  }
  const size_t i = off + blockIdx.x * 256 + threadIdx.x;
  const float4* p = (const float4*)in;
  float4 a = p[2 * i], b = p[2 * i + 1];
  short8 o;
  o[0] = f2bf(a.x); o[1] = f2bf(a.y); o[2] = f2bf(a.z); o[3] = f2bf(a.w);
  o[4] = f2bf(b.x); o[5] = f2bf(b.y); o[6] = f2bf(b.z); o[7] = f2bf(b.w);
  ((short8*)out)[i] = o;
}

// ---- QKV GEMM: 128x128 tile, BK=64, 8 waves, mfma 32x32x16 -----------------
// Wave w: rows (w>>1)*32, cols (w&1)*64 (2 n-frags of 32). Per kstep (K16):
// 1 af + 2 bf ds_read_b128 + 2 mfma32. C-layout: col=l&31,
// row = (reg&3) + 8*(reg>>2) + 4*(l>>5).
// EP0: Q scaled bf16 row-major.
// EP1: K folded, fragment layout: per (b,h) [u=s>>5][c=d>>3][lo=s&31][j=d&7]
// EP2: V^T fragment layout: per (b,h) [T=s>>6][w2=d>>5][c=(s>>3)&7][dlo=d&31][j=s&7]
constexpr int GK = 1024, GN = 1024;
constexpr float QSCALE = 0.125f * 1.44269504088896340736f;  // SCALE * log2(e)

template <int EP>
__device__ __forceinline__ void gemm_body(char* lds, const short* __restrict__ A,
                                          const short* __restrict__ W,
                                          const float* __restrict__ bias,
                                          void* __restrict__ C,
                                          const float* __restrict__ mwp) {
  const int tid = threadIdx.x;
  const int l = tid & 63, w = tid >> 6;
  const int lo = l & 31, hi = l >> 5;
  const int wr = w >> 1, wc = w & 1;
  const int m0 = blockIdx.y * 128, n0 = blockIdx.x * 128;

  f32x16 acc[2] = {};

  const int srow = tid >> 3, sc8 = tid & 7, wv = tid >> 6;
  for (int kb = 0; kb < GK / 64; ++kb) {
    const int k0 = kb * 64;
#pragma unroll
    for (int p = 0; p < 2; ++p) {
      const int ra = p * 64 + srow;
      gload_lds16(A + (size_t)(m0 + ra) * GK + k0 + ((sc8 ^ (ra & 7)) * 8),
                  lds + p * 8192 + wv * 1024);
      gload_lds16(W + (size_t)(n0 + ra) * GK + k0 + ((sc8 ^ (ra & 7)) * 8),
                  lds + 16384 + p * 8192 + wv * 1024);
    }
    __syncthreads();
#pragma unroll
    for (int ks = 0; ks < 4; ++ks) {  // K16 steps
      const int chunk = ks * 2 + hi;
      const int mt = wr * 32 + lo;
      bf16x8 af = *(const bf16x8*)(lds + mt * 128 + ((chunk ^ (mt & 7)) * 16));
#pragma unroll
      for (int nf = 0; nf < 2; ++nf) {
        const int nt = wc * 64 + nf * 32 + lo;
        bf16x8 bf =
            *(const bf16x8*)(lds + 16384 + nt * 128 + ((chunk ^ (nt & 7)) * 16));
        acc[nf] = mfma32(af, bf, acc[nf]);
      }
    }
    __syncthreads();
  }

  const float mwv = (EP == 1) ? mwp[0] : 0.f;
  const int mb = m0 + wr * 32 + 4 * hi;
#pragma unroll
  for (int nf = 0; nf < 2; ++nf) {
    const int n = n0 + wc * 64 + nf * 32 + lo;
    const float bv = bias[n];
    if (EP == 1) {  // K~ fragment layout, scalar stores (partner = nf^1)
      const float bv2 = bias[n ^ 32];
      const int h = n >> 6, c = (n >> 3) & 7, j = n & 7;
#pragma unroll
      for (int r = 0; r < 16; ++r) {
        const int m = mb + (r & 3) + 8 * (r >> 2);
        const int b = m >> 11, s = m & 2047;
        const float v = acc[nf][r] + bv + mwv * (acc[nf ^ 1][r] + bv2);
        ((short*)C)[(size_t)(b * 16 + h) * 131072 + (s >> 5) * 2048 + c * 256 +
                    (s & 31) * 8 + j] = f2bf(v);
      }
    } else if (EP == 2) {  // V^T fragment layout, s16x4 stores (4 consec s)
      const int h = n >> 6, w2 = (n >> 5) & 1, dlo = n & 31;
#pragma unroll
      for (int g = 0; g < 4; ++g) {
        const int m = mb + 8 * g;  // rows m..m+3 (reg 4g..4g+3)
        const int b = m >> 11, s = m & 2047;
        s16x4 v;
#pragma unroll
        for (int r = 0; r < 4; ++r) v[r] = f2bf(acc[nf][g * 4 + r] + bv);
        *(s16x4*)((short*)C + (size_t)(b * 16 + h) * 131072 + (s >> 6) * 4096 +
                  w2 * 2048 + ((s >> 3) & 7) * 256 + dlo * 8 + (s & 7)) = v;
      }
    } else {  // EP0: Q scaled bf16 row-major
#pragma unroll
      for (int r = 0; r < 16; ++r) {
        const int m = mb + (r & 3) + 8 * (r >> 2);
        ((short*)C)[(size_t)m * GN + n] = f2bf((acc[nf][r] + bv) * QSCALE);
      }
    }
  }
}

__global__ __launch_bounds__(512, 4) void gemm_qkv_kernel(
    const short* __restrict__ A, const short* Wq, const short* Wk, const short* Wv,
    const float* bq, const float* bk, const float* bv, short* q, short* kf,
    short* vf, const float* mw) {
  __shared__ __align__(16) char lds[32768];
  if (blockIdx.z == 0) gemm_body<0>(lds, A, Wq, bq, q, nullptr);
  else if (blockIdx.z == 1) gemm_body<1>(lds, A, Wk, bk, kf, mw);
  else gemm_body<2>(lds, A, Wv, bv, vf, nullptr);
}

// ---- out GEMM: 64x128 tile, BK=64, 8 waves (wave = 32x32), mfma32 ----------
__global__ __launch_bounds__(512, 4) void gemm_out_kernel(const short* __restrict__ A,
                                                          const short* __restrict__ W,
                                                          const float* __restrict__ bias,
                                                          float* __restrict__ C) {
  __shared__ __align__(16) char lds[24576];  // A 8KB | W 16KB
  const int tid = threadIdx.x;
  const int l = tid & 63, w = tid >> 6;
  const int lo = l & 31, hi = l >> 5;
  const int wr = w >> 2, wc = w & 3;  // wave = rows wr*32, cols wc*32
  const int m0 = blockIdx.y * 64, n0 = blockIdx.x * 128;

  f32x16 acc = {};

  const int srow = tid >> 3, sc8 = tid & 7, wv = tid >> 6;
  const int sra = srow & 63;  // A staging row
  for (int kb = 0; kb < GK / 64; ++kb) {
    const int k0 = kb * 64;
    gload_lds16(A + (size_t)(m0 + sra) * GK + k0 + ((sc8 ^ (sra & 7)) * 8),
                lds + wv * 1024);
#pragma unroll
    for (int p = 0; p < 2; ++p) {
      const int rw = p * 64 + srow;
      gload_lds16(W + (size_t)(n0 + rw) * GK + k0 + ((sc8 ^ (rw & 7)) * 8),
                  lds + 8192 + p * 8192 + wv * 1024);
    }
    __syncthreads();
#pragma unroll
    for (int ks = 0; ks < 4; ++ks) {
      const int chunk = ks * 2 + hi;
      const int mt = wr * 32 + lo;
      const int nt = wc * 32 + lo;
      bf16x8 af = *(const bf16x8*)(lds + mt * 128 + ((chunk ^ (mt & 7)) * 16));
      bf16x8 bf =
          *(const bf16x8*)(lds + 8192 + nt * 128 + ((chunk ^ (nt & 7)) * 16));
      acc = mfma32(af, bf, acc);
    }
    __syncthreads();
  }

  const int n = n0 + wc * 32 + lo;
  const int mb = m0 + wr * 32 + 4 * hi;
  const float bv = bias[n];
#pragma unroll
  for (int r = 0; r < 16; ++r) {
    const int m = mb + (r & 3) + 8 * (r >> 2);
    C[(size_t)m * GN + n] = acc[r] + bv;
  }
}

// ---- flash attention: r12 structure (plateau best: ~55us) ------------------
// 1024 WGs x 256 thr (4 warps). Warp w: q-sub (w&1), kv-parity (w>>1).
// kf[0..7] = even-local-tile bank, kf[8..15] = odd bank (2-deep K prefetch);
// vf 1-deep. setprio(1) wraps MFMA clusters. (256,2): no spill at kf[16].
__global__ __launch_bounds__(256, 2) void attn_kernel(const short* __restrict__ Q,
                                                      const short* __restrict__ Kf,
                                                      const short* __restrict__ Vf,
                                                      short* __restrict__ O) {
  constexpr int S = 2048;
  constexpr int NT = S / 128;  // local tiles per parity (16)
  __shared__ float mbuf[2][32][64];
  __shared__ float lbuf[64];
  const int tid = threadIdx.x;
  const int l = tid & 63, w = tid >> 6;
  const int lo = l & 31, hi = l >> 5;
  const int wq = w & 1, par = w >> 1;
  const int bid = blockIdx.x;
  const int sub = bid >> 3;
  const int x = sub & 31;
  const int y = (bid & 7) * 4 + (sub >> 5);  // bh index; 4 bh per XCD
  const int b = y >> 4, h = y & 15;
  const int q0 = x * 64 + wq * 32;
  const size_t base = (size_t)b * S * 1024 + h * 64;  // Q/O row-major
  const size_t fbase = (size_t)y * 131072;            // Kf/Vf per-bh block

  // Q fragments: lane holds Q[q0+lo][ds*16 + hi*8 + j]
  bf16x8 qf[4];
  {
    const short* qp = Q + base + (size_t)(q0 + lo) * 1024 + hi * 8;
#pragma unroll
    for (int ds = 0; ds < 4; ++ds) qf[ds] = *(const bf16x8*)(qp + ds * 16);
  }

  const int voff = hi * 256 + lo * 8;  // element offset within a 1KB frag group
  const short* kpe = Kf + fbase + par * 4096 + voff;  // even local tiles
  const short* kpo = kpe + 8192;                      // odd local tiles
  const short* vpn = Vf + fbase + par * 4096 + voff;

  bf16x8 kf[16], vf[8];
#pragma unroll
  for (int ds = 0; ds < 4; ++ds) {
    kf[ds]      = *(const bf16x8*)(kpe + ds * 512);
    kf[4 + ds]  = *(const bf16x8*)(kpe + 2048 + ds * 512);
    kf[8 + ds]  = *(const bf16x8*)(kpo + ds * 512);
    kf[12 + ds] = *(const bf16x8*)(kpo + 2048 + ds * 512);
    vf[ds]      = *(const bf16x8*)(vpn + ds * 512);
    vf[4 + ds]  = *(const bf16x8*)(vpn + 2048 + ds * 512);
  }
  kpe += 16384;  // -> local tile 2
  kpo += 16384;  // -> local tile 3
  vpn += 8192;   // -> local tile 1

  f32x16 o0 = {}, o1 = {};  // O^T: d 0-31 / 32-63 rows, q = lo col
  float lrow = 0.f;         // lane-local partial; cross-32 merged at end

  // prologue: QK(0) from even bank, then refill even bank with K(2)
  f32x16 st0 = {}, st1 = {};
  __builtin_amdgcn_s_setprio(1);
#pragma unroll
  for (int ds = 0; ds < 4; ++ds) {
    st0 = mfma32(kf[ds], qf[ds], st0);
    st1 = mfma32(kf[4 + ds], qf[ds], st1);
  }
  __builtin_amdgcn_s_setprio(0);
#pragma unroll
  for (int ds = 0; ds < 4; ++ds) {
    kf[ds]     = *(const bf16x8*)(kpe + ds * 512);
    kf[4 + ds] = *(const bf16x8*)(kpe + 2048 + ds * 512);
  }
  kpe += 16384;

  // softmax + pack macro body (operates on st0/st1 -> pf, updates lrow)
#define SOFTPACK(pf)                                                          \
  {                                                                           \
    _Pragma("unroll") for (int r = 0; r < 16; ++r) st0[r] = exp2fa(st0[r]);   \
    _Pragma("unroll") for (int r = 0; r < 16; ++r) st1[r] = exp2fa(st1[r]);   \
    float ts[8];                                                              \
    _Pragma("unroll") for (int r = 0; r < 8; ++r) ts[r] =                     \
        (st0[r] + st0[r + 8]) + (st1[r] + st1[r + 8]);                        \
    _Pragma("unroll") for (int d = 4; d >= 1; d >>= 1)                        \
        _Pragma("unroll") for (int r = 0; r < 4; ++r)                         \
        if (r < d) ts[r] += ts[r + d];                                        \
    lrow += ts[0];                                                            \
    pf[0] = pack8(st0[0], st0[1], st0[2], st0[3], st0[4], st0[5], st0[6],     \
                  st0[7]);                                                    \
    pf[1] = pack8(st0[8], st0[9], st0[10], st0[11], st0[12], st0[13],         \
                  st0[14], st0[15]);                                          \
    pf[2] = pack8(st1[0], st1[1], st1[2], st1[3], st1[4], st1[5], st1[6],     \
                  st1[7]);                                                    \
    pf[3] = pack8(st1[8], st1[9], st1[10], st1[11], st1[12], st1[13],         \
                  st1[14], st1[15]);                                          \
  }

  for (int ii = 0; ii < NT / 2 - 1; ++ii) {
    // ---- sub-iter A: i = 2*ii (even). QK(i+1) from ODD bank; PV(i) ----------
    {
      bf16x8 pf[4];
      SOFTPACK(pf);
      __builtin_amdgcn_s_setprio(1);
#pragma unroll
      for (int r = 0; r < 16; ++r) { st0[r] = 0.f; st1[r] = 0.f; }
#pragma unroll
      for (int ds = 0; ds < 4; ++ds) {
        st0 = mfma32(kf[8 + ds], qf[ds], st0);
        st1 = mfma32(kf[12 + ds], qf[ds], st1);
      }
#pragma unroll
      for (int kv = 0; kv < 4; ++kv) {
        o0 = mfma32(vf[kv], pf[kv], o0);
        o1 = mfma32(vf[4 + kv], pf[kv], o1);
      }
      __builtin_amdgcn_s_setprio(0);
      // refill odd bank with K(i+3); vf with V(i+1)
#pragma unroll
      for (int ds = 0; ds < 4; ++ds) {
        kf[8 + ds]  = *(const bf16x8*)(kpo + ds * 512);
        kf[12 + ds] = *(const bf16x8*)(kpo + 2048 + ds * 512);
        vf[ds]      = *(const bf16x8*)(vpn + ds * 512);
        vf[4 + ds]  = *(const bf16x8*)(vpn + 2048 + ds * 512);
      }
      kpo += 16384;
      vpn += 8192;
    }
    // ---- sub-iter B: i = 2*ii+1 (odd). QK(i+1) from EVEN bank; PV(i) --------
    {
      bf16x8 pf[4];
      SOFTPACK(pf);
      __builtin_amdgcn_s_setprio(1);
#pragma unroll
      for (int r = 0; r < 16; ++r) { st0[r] = 0.f; st1[r] = 0.f; }
#pragma unroll
      for (int ds = 0; ds < 4; ++ds) {
        st0 = mfma32(kf[ds], qf[ds], st0);
        st1 = mfma32(kf[4 + ds], qf[ds], st1);
      }
#pragma unroll
      for (int kv = 0; kv < 4; ++kv) {
        o0 = mfma32(vf[kv], pf[kv], o0);
        o1 = mfma32(vf[4 + kv], pf[kv], o1);
      }
      __builtin_amdgcn_s_setprio(0);
      // refill even bank with K(i+3) (last one over-reads: allocated ws);
      // vf with V(i+1)
#pragma unroll
      for (int ds = 0; ds < 4; ++ds) {
        kf[ds]     = *(const bf16x8*)(kpe + ds * 512);
        kf[4 + ds] = *(const bf16x8*)(kpe + 2048 + ds * 512);
        vf[ds]     = *(const bf16x8*)(vpn + ds * 512);
        vf[4 + ds] = *(const bf16x8*)(vpn + 2048 + ds * 512);
      }
      kpe += 16384;
      vpn += 8192;
    }
  }

  // tail: i = NT-2 (even): softmax; QK(NT-1) from odd bank + PV; refill vf
  {
    bf16x8 pf[4];
    SOFTPACK(pf);
    __builtin_amdgcn_s_setprio(1);
#pragma unroll
    for (int r = 0; r < 16; ++r) { st0[r] = 0.f; st1[r] = 0.f; }
#pragma unroll
    for (int ds = 0; ds < 4; ++ds) {
      st0 = mfma32(kf[8 + ds], qf[ds], st0);
      st1 = mfma32(kf[12 + ds], qf[ds], st1);
    }
#pragma unroll
    for (int kv = 0; kv < 4; ++kv) {
      o0 = mfma32(vf[kv], pf[kv], o0);
      o1 = mfma32(vf[4 + kv], pf[kv], o1);
    }
    __builtin_amdgcn_s_setprio(0);
#pragma unroll
    for (int ds = 0; ds < 4; ++ds) {
      vf[ds]     = *(const bf16x8*)(vpn + ds * 512);
      vf[4 + ds] = *(const bf16x8*)(vpn + 2048 + ds * 512);
    }
  }
  // tail: i = NT-1: softmax + PV only
  {
    bf16x8 pf[4];
    SOFTPACK(pf);
    __builtin_amdgcn_s_setprio(1);
#pragma unroll
    for (int kv = 0; kv < 4; ++kv) {
      o0 = mfma32(vf[kv], pf[kv], o0);
      o1 = mfma32(vf[4 + kv], pf[kv], o1);
    }
    __builtin_amdgcn_s_setprio(0);
  }
#undef SOFTPACK

  lrow += __shfl_xor(lrow, 32);  // full row sum for this parity

  // ---- merge kv-parities: par 1 -> LDS, par 0 adds + writes -----------------
  if (par == 1) {
#pragma unroll
    for (int g = 0; g < 4; ++g) {
      const int c0 = (2 * g + hi) ^ (lo & 15);  // swizzled 16B chunk
      const int c1 = (8 + 2 * g + hi) ^ (lo & 15);
      f32x4 v0, v1;
#pragma unroll
      for (int r = 0; r < 4; ++r) { v0[r] = o0[g * 4 + r]; v1[r] = o1[g * 4 + r]; }
      *(f32x4*)(&mbuf[wq][lo][c0 * 4]) = v0;
      *(f32x4*)(&mbuf[wq][lo][c1 * 4]) = v1;
    }
    if (hi == 0) lbuf[wq * 32 + lo] = lrow;
  }
  __syncthreads();
  if (par == 0) {
#pragma unroll
    for (int g = 0; g < 4; ++g) {
      const int c0 = (2 * g + hi) ^ (lo & 15);
      const int c1 = (8 + 2 * g + hi) ^ (lo & 15);
      f32x4 v0 = *(const f32x4*)(&mbuf[wq][lo][c0 * 4]);
      f32x4 v1 = *(const f32x4*)(&mbuf[wq][lo][c1 * 4]);
#pragma unroll
      for (int r = 0; r < 4; ++r) { o0[g * 4 + r] += v0[r]; o1[g * 4 + r] += v1[r]; }
    }
    const float inv = 1.0f / (lrow + lbuf[wq * 32 + lo]);
    short* Op = O + base + (size_t)(q0 + lo) * 1024;
#pragma unroll
    for (int g = 0; g < 4; ++g) {
      s16x4 v0, v1;
#pragma unroll
      for (int r = 0; r < 4; ++r) {
        v0[r] = f2bf(o0[g * 4 + r] * inv);
        v1[r] = f2bf(o1[g * 4 + r] * inv);
      }
      *(s16x4*)(Op + 8 * g + 4 * hi) = v0;
      *(s16x4*)(Op + 32 + 8 * g + 4 * hi) = v1;
    }
  }
}

// ---------------------------------------------------------------------------
extern "C" void kernel_launch(void* const* d_in, const int* in_sizes, int n_in,
                              void* d_out, int out_size, void* d_ws, size_t ws_size,
                              hipStream_t stream) {
  const float* x  = (const float*)d_in[0];
  const float* Wq = (const float*)d_in[1];
  const float* bq = (const float*)d_in[2];
  const float* Wk = (const float*)d_in[3];
  const float* bk = (const float*)d_in[4];
  const float* Wv = (const float*)d_in[5];
  const float* bv = (const float*)d_in[6];
  const float* Wo = (const float*)d_in[7];
  const float* bo = (const float*)d_in[8];
  const float* mw = (const float*)d_in[9];
  float* out = (float*)d_out;
  char* ws = (char*)d_ws;
  const size_t MB = (size_t)1 << 20;

  short* xb  = (short*)(ws + 0 * MB);   // 4096x1024 bf16
  short* wqb = (short*)(ws + 8 * MB);
  short* wkb = (short*)(ws + 10 * MB);
  short* wvb = (short*)(ws + 12 * MB);
  short* wob = (short*)(ws + 14 * MB);
  short* qb  = (short*)(ws + 16 * MB);  // scaled Q, row-major
  short* kfb = (short*)(ws + 24 * MB);  // K~ fragment layout (8 MB)
  short* vfb = (short*)(ws + 32 * MB);  // V^T fragment layout (8 MB)
  short* ob  = (short*)(ws + 40 * MB);  // attn out bf16

  cast_all_kernel<<<dim3(512, 8), 256, 0, stream>>>(x, Wq, Wk, Wv, Wo, xb, wqb,
                                                    wkb, wvb, wob);
  gemm_qkv_kernel<<<dim3(8, 32, 3), 512, 0, stream>>>(xb, wqb, wkb, wvb, bq, bk, bv,
                                                      qb, kfb, vfb, mw);
  attn_kernel<<<1024, 256, 0, stream>>>(qb, kfb, vfb, ob);
  gemm_out_kernel<<<dim3(8, 64), 512, 0, stream>>>(ob, wob, bo, out);
}

// Round 14
// 114.155 us; speedup vs baseline: 1.0518x; 1.0518x over previous
//
#include <hip/hip_runtime.h>

// ---------------------------------------------------------------------------
// IncidenceAttention. incidence = (Q·K~^T)*SCALE with K~[d] = K[d] + mw*K[d^32].
// Pipeline: cast -> QKV gemm (8-wave 128^2 tiles, mfma 16x16x32) -> flash attn
//           (2-deep-K register prefetch, (256,2), setprio clusters) ->
//           out gemm (64x128 tiles, mfma 16x16x32).
// R14: revert of r13's mfma32 GEMM experiment (regressed +6us: GEMMs are
// 2-phase staging-bound, not MFMA-issue-bound). This is the r12 best config
// (114.66us): attn plateau-proven across 7 variants; GEMMs at the 2-phase
// structural ceiling; cast at BW.
// ---------------------------------------------------------------------------

typedef __attribute__((ext_vector_type(8))) short short8;
typedef __attribute__((ext_vector_type(4))) short s16x4;
typedef __attribute__((ext_vector_type(4))) float f32x4;
typedef __attribute__((ext_vector_type(16))) float f32x16;
typedef __attribute__((ext_vector_type(8))) __bf16 bf16x8;
typedef __attribute__((ext_vector_type(4))) unsigned uint4v;

__device__ __forceinline__ float exp2fa(float x) {
  return __builtin_amdgcn_exp2f(x);  // v_exp_f32: 2^x
}
__device__ __forceinline__ short f2bf(float f) {
  unsigned u = __builtin_bit_cast(unsigned, f);
  u = u + 0x7fffu + ((u >> 16) & 1u);  // RNE
  return (short)(u >> 16);
}
__device__ __forceinline__ f32x4 mfma16(bf16x8 a, bf16x8 b, f32x4 c) {
  return __builtin_amdgcn_mfma_f32_16x16x32_bf16(a, b, c, 0, 0, 0);
}
__device__ __forceinline__ f32x16 mfma32(bf16x8 a, bf16x8 b, f32x16 c) {
  return __builtin_amdgcn_mfma_f32_32x32x16_bf16(a, b, c, 0, 0, 0);
}
__device__ __forceinline__ void gload_lds16(const void* g, void* l) {
  __builtin_amdgcn_global_load_lds(
      (const __attribute__((address_space(1))) unsigned int*)g,
      (__attribute__((address_space(3))) unsigned int*)l, 16, 0, 0);
}
__device__ __forceinline__ unsigned pkbf(float a, float b) {
  unsigned r;
  asm("v_cvt_pk_bf16_f32 %0, %1, %2" : "=v"(r) : "v"(a), "v"(b));
  return r;
}
__device__ __forceinline__ void plswap(unsigned& a, unsigned& b) {
  asm volatile("v_permlane32_swap_b32 %0, %1" : "+v"(a), "+v"(b));
}
// pack 8 f32 P values into the PV B-operand fragment (m214 T12 pattern).
__device__ __forceinline__ bf16x8 pack8(float x0, float x1, float x2, float x3,
                                        float x4, float x5, float x6, float x7) {
  unsigned a0 = pkbf(x0, x1), a1 = pkbf(x2, x3);
  unsigned a2 = pkbf(x4, x5), a3 = pkbf(x6, x7);
  plswap(a0, a2);
  plswap(a1, a3);
  uint4v u = {a0, a1, a2, a3};
  return __builtin_bit_cast(bf16x8, u);
}

// ---- merged cast: x (4 chunks) + 4 weight matrices, one launch -------------
__global__ void cast_all_kernel(const float* x, const float* w0, const float* w1,
                                const float* w2, const float* w3, short* xo,
                                short* o0, short* o1, short* o2, short* o3) {
  const float* in; short* out;
  const int r = blockIdx.y;
  size_t off;
  if (r < 4) { in = x; out = xo; off = (size_t)r * 131072; }
  else {
    switch (r) {
      case 4: in = w0; out = o0; break;
      case 5: in = w1; out = o1; break;
      case 6: in = w2; out = o2; break;
      default: in = w3; out = o3; break;
    }
    off = 0;
  }
  const size_t i = off + blockIdx.x * 256 + threadIdx.x;
  const float4* p = (const float4*)in;
  float4 a = p[2 * i], b = p[2 * i + 1];
  short8 o;
  o[0] = f2bf(a.x); o[1] = f2bf(a.y); o[2] = f2bf(a.z); o[3] = f2bf(a.w);
  o[4] = f2bf(b.x); o[5] = f2bf(b.y); o[6] = f2bf(b.z); o[7] = f2bf(b.w);
  ((short8*)out)[i] = o;
}

// ---- QKV GEMM: 128x128 tile, BK=64, 8 waves (wave = 64x32), mfma16 ---------
// EP0: Q scaled bf16 row-major.
// EP1: K folded, fragment layout: per (b,h) [u=s>>5][c=d>>3][lo=s&31][j=d&7]
// EP2: V^T fragment layout: per (b,h) [T=s>>6][w2=d>>5][c=(s>>3)&7][dlo=d&31][j=s&7]
constexpr int GK = 1024, GN = 1024;
constexpr float QSCALE = 0.125f * 1.44269504088896340736f;  // SCALE * log2(e)

template <int EP>
__device__ __forceinline__ void gemm_body(char* lds, const short* __restrict__ A,
                                          const short* __restrict__ W,
                                          const float* __restrict__ bias,
                                          void* __restrict__ C,
                                          const float* __restrict__ mwp) {
  const int tid = threadIdx.x;
  const int l = tid & 63, w = tid >> 6;
  const int wr = w >> 2, wc = w & 3;
  const int ncb = (wc >> 1) * 64 + (wc & 1) * 16;  // wave col base
  const int m0 = blockIdx.y * 128, n0 = blockIdx.x * 128;

  f32x4 acc[4][2] = {};

  const int srow = tid >> 3, sc8 = tid & 7, wv = tid >> 6;
  for (int kb = 0; kb < GK / 64; ++kb) {
    const int k0 = kb * 64;
#pragma unroll
    for (int p = 0; p < 2; ++p) {
      const int ra = p * 64 + srow;
      gload_lds16(A + (size_t)(m0 + ra) * GK + k0 + ((sc8 ^ (ra & 7)) * 8),
                  lds + p * 8192 + wv * 1024);
      gload_lds16(W + (size_t)(n0 + ra) * GK + k0 + ((sc8 ^ (ra & 7)) * 8),
                  lds + 16384 + p * 8192 + wv * 1024);
    }
    __syncthreads();
#pragma unroll
    for (int ks = 0; ks < 2; ++ks) {
      bf16x8 af[4], bfr[2];
      const int chunk = ks * 4 + (l >> 4);
#pragma unroll
      for (int mf = 0; mf < 4; ++mf) {
        const int mt = wr * 64 + mf * 16 + (l & 15);
        af[mf] = *(const bf16x8*)(lds + mt * 128 + ((chunk ^ (mt & 7)) * 16));
      }
#pragma unroll
      for (int nf = 0; nf < 2; ++nf) {
        const int nt = ncb + nf * 32 + (l & 15);
        bfr[nf] = *(const bf16x8*)(lds + 16384 + nt * 128 + ((chunk ^ (nt & 7)) * 16));
      }
#pragma unroll
      for (int mf = 0; mf < 4; ++mf)
#pragma unroll
        for (int nf = 0; nf < 2; ++nf)
          acc[mf][nf] = mfma16(af[mf], bfr[nf], acc[mf][nf]);
    }
    __syncthreads();
  }

  const float mwv = (EP == 1) ? mwp[0] : 0.f;
#pragma unroll
  for (int mf = 0; mf < 4; ++mf)
#pragma unroll
    for (int nf = 0; nf < 2; ++nf) {
      const int n = n0 + ncb + nf * 32 + (l & 15);
      const int mb = m0 + wr * 64 + mf * 16 + (l >> 4) * 4;
      if (EP == 1) {  // K~ fragment layout, scalar stores (partner = nf^1)
        const float bv = bias[n], bv2 = bias[n ^ 32];
        const int h = n >> 6, c = (n >> 3) & 7, j = n & 7;
#pragma unroll
        for (int r = 0; r < 4; ++r) {
          const int m = mb + r;
          const int b = m >> 11, s = m & 2047;
          const float v =
              acc[mf][nf][r] + bv + mwv * (acc[mf][nf ^ 1][r] + bv2);
          ((short*)C)[(size_t)(b * 16 + h) * 131072 + (s >> 5) * 2048 + c * 256 +
                      (s & 31) * 8 + j] = f2bf(v);
        }
      } else if (EP == 2) {  // V^T fragment layout, s16x4 stores
        const int h = n >> 6, w2 = (n >> 5) & 1, dlo = n & 31;
        s16x4 v;
#pragma unroll
        for (int r = 0; r < 4; ++r) v[r] = f2bf(acc[mf][nf][r] + bias[n]);
        const int b = mb >> 11, s = mb & 2047;
        *(s16x4*)((short*)C + (size_t)(b * 16 + h) * 131072 + (s >> 6) * 4096 +
                  w2 * 2048 + ((s >> 3) & 7) * 256 + dlo * 8 + (s & 7)) = v;
      } else {
        const float bv = bias[n];
#pragma unroll
        for (int r = 0; r < 4; ++r) {
          const int m = mb + r;
          float v = acc[mf][nf][r] + bv;
          if (EP == 0) v *= QSCALE;
          ((short*)C)[(size_t)m * GN + n] = f2bf(v);
        }
      }
    }
}

__global__ __launch_bounds__(512, 4) void gemm_qkv_kernel(
    const short* __restrict__ A, const short* Wq, const short* Wk, const short* Wv,
    const float* bq, const float* bk, const float* bv, short* q, short* kf,
    short* vf, const float* mw) {
  __shared__ __align__(16) char lds[32768];
  if (blockIdx.z == 0) gemm_body<0>(lds, A, Wq, bq, q, nullptr);
  else if (blockIdx.z == 1) gemm_body<1>(lds, A, Wk, bk, kf, mw);
  else gemm_body<2>(lds, A, Wv, bv, vf, nullptr);
}

// ---- out GEMM: 64x128 tile, BK=64, 8 waves (wave = 32x32), 512 WGs ---------
__global__ __launch_bounds__(512, 4) void gemm_out_kernel(const short* __restrict__ A,
                                                          const short* __restrict__ W,
                                                          const float* __restrict__ bias,
                                                          float* __restrict__ C) {
  __shared__ __align__(16) char lds[24576];  // A 8KB | W 16KB
  const int tid = threadIdx.x;
  const int l = tid & 63, w = tid >> 6;
  const int wr = w >> 2, wc = w & 3;  // wave = rows wr*32, cols wc*32
  const int m0 = blockIdx.y * 64, n0 = blockIdx.x * 128;

  f32x4 acc[2][2] = {};

  const int srow = tid >> 3, sc8 = tid & 7, wv = tid >> 6;
  const int sra = srow & 63;  // A staging row (one chunk per thread)
  for (int kb = 0; kb < GK / 64; ++kb) {
    const int k0 = kb * 64;
    gload_lds16(A + (size_t)(m0 + sra) * GK + k0 + ((sc8 ^ (sra & 7)) * 8),
                lds + wv * 1024);
#pragma unroll
    for (int p = 0; p < 2; ++p) {
      const int rw = p * 64 + srow;
      gload_lds16(W + (size_t)(n0 + rw) * GK + k0 + ((sc8 ^ (rw & 7)) * 8),
                  lds + 8192 + p * 8192 + wv * 1024);
    }
    __syncthreads();
#pragma unroll
    for (int ks = 0; ks < 2; ++ks) {
      bf16x8 af[2], bfr[2];
      const int chunk = ks * 4 + (l >> 4);
#pragma unroll
      for (int mf = 0; mf < 2; ++mf) {
        const int mt = wr * 32 + mf * 16 + (l & 15);
        af[mf] = *(const bf16x8*)(lds + mt * 128 + ((chunk ^ (mt & 7)) * 16));
      }
#pragma unroll
      for (int nf = 0; nf < 2; ++nf) {
        const int nt = wc * 32 + nf * 16 + (l & 15);
        bfr[nf] = *(const bf16x8*)(lds + 8192 + nt * 128 + ((chunk ^ (nt & 7)) * 16));
      }
#pragma unroll
      for (int mf = 0; mf < 2; ++mf)
#pragma unroll
        for (int nf = 0; nf < 2; ++nf)
          acc[mf][nf] = mfma16(af[mf], bfr[nf], acc[mf][nf]);
    }
    __syncthreads();
  }

#pragma unroll
  for (int mf = 0; mf < 2; ++mf)
#pragma unroll
    for (int nf = 0; nf < 2; ++nf) {
      const int n = n0 + wc * 32 + nf * 16 + (l & 15);
      const int mb = m0 + wr * 32 + mf * 16 + (l >> 4) * 4;
      const float bv = bias[n];
#pragma unroll
      for (int r = 0; r < 4; ++r)
        C[(size_t)(mb + r) * GN + n] = acc[mf][nf][r] + bv;
    }
}

// ---- flash attention: K 2-deep prefetch, (256,2) so kf[16] fits ------------
// 1024 WGs x 256 thr (4 warps). Warp w: q-sub (w&1), kv-parity (w>>1).
// kf[0..7] = even-local-tile bank, kf[8..15] = odd bank; refilled right after
// their cluster use (gap ~2 sub-iters). vf 1-deep. setprio(1) wraps each
// MFMA cluster (r8: removing it cost 1.6x). No spill at (256,2).
__global__ __launch_bounds__(256, 2) void attn_kernel(const short* __restrict__ Q,
                                                      const short* __restrict__ Kf,
                                                      const short* __restrict__ Vf,
                                                      short* __restrict__ O) {
  constexpr int S = 2048;
  constexpr int NT = S / 128;  // local tiles per parity (16)
  __shared__ float mbuf[2][32][64];
  __shared__ float lbuf[64];
  const int tid = threadIdx.x;
  const int l = tid & 63, w = tid >> 6;
  const int lo = l & 31, hi = l >> 5;
  const int wq = w & 1, par = w >> 1;
  const int bid = blockIdx.x;
  const int sub = bid >> 3;
  const int x = sub & 31;
  const int y = (bid & 7) * 4 + (sub >> 5);  // bh index; 4 bh per XCD
  const int b = y >> 4, h = y & 15;
  const int q0 = x * 64 + wq * 32;
  const size_t base = (size_t)b * S * 1024 + h * 64;  // Q/O row-major
  const size_t fbase = (size_t)y * 131072;            // Kf/Vf per-bh block

  // Q fragments: lane holds Q[q0+lo][ds*16 + hi*8 + j]
  bf16x8 qf[4];
  {
    const short* qp = Q + base + (size_t)(q0 + lo) * 1024 + hi * 8;
#pragma unroll
    for (int ds = 0; ds < 4; ++ds) qf[ds] = *(const bf16x8*)(qp + ds * 16);
  }

  const int voff = hi * 256 + lo * 8;  // element offset within a 1KB frag group
  const short* kpe = Kf + fbase + par * 4096 + voff;  // even local tiles
  const short* kpo = kpe + 8192;                      // odd local tiles
  const short* vpn = Vf + fbase + par * 4096 + voff;

  bf16x8 kf[16], vf[8];
#pragma unroll
  for (int ds = 0; ds < 4; ++ds) {
    kf[ds]      = *(const bf16x8*)(kpe + ds * 512);
    kf[4 + ds]  = *(const bf16x8*)(kpe + 2048 + ds * 512);
    kf[8 + ds]  = *(const bf16x8*)(kpo + ds * 512);
    kf[12 + ds] = *(const bf16x8*)(kpo + 2048 + ds * 512);
    vf[ds]      = *(const bf16x8*)(vpn + ds * 512);
    vf[4 + ds]  = *(const bf16x8*)(vpn + 2048 + ds * 512);
  }
  kpe += 16384;  // -> local tile 2
  kpo += 16384;  // -> local tile 3
  vpn += 8192;   // -> local tile 1

  f32x16 o0 = {}, o1 = {};  // O^T: d 0-31 / 32-63 rows, q = lo col
  float lrow = 0.f;         // lane-local partial; cross-32 merged at end

  // prologue: QK(0) from even bank, then refill even bank with K(2)
  f32x16 st0 = {}, st1 = {};
  __builtin_amdgcn_s_setprio(1);
#pragma unroll
  for (int ds = 0; ds < 4; ++ds) {
    st0 = mfma32(kf[ds], qf[ds], st0);
    st1 = mfma32(kf[4 + ds], qf[ds], st1);
  }
  __builtin_amdgcn_s_setprio(0);
#pragma unroll
  for (int ds = 0; ds < 4; ++ds) {
    kf[ds]     = *(const bf16x8*)(kpe + ds * 512);
    kf[4 + ds] = *(const bf16x8*)(kpe + 2048 + ds * 512);
  }
  kpe += 16384;

  // softmax + pack macro body (operates on st0/st1 -> pf, updates lrow)
#define SOFTPACK(pf)                                                          \
  {                                                                           \
    _Pragma("unroll") for (int r = 0; r < 16; ++r) st0[r] = exp2fa(st0[r]);   \
    _Pragma("unroll") for (int r = 0; r < 16; ++r) st1[r] = exp2fa(st1[r]);   \
    float ts[8];                                                              \
    _Pragma("unroll") for (int r = 0; r < 8; ++r) ts[r] =                     \
        (st0[r] + st0[r + 8]) + (st1[r] + st1[r + 8]);                        \
    _Pragma("unroll") for (int d = 4; d >= 1; d >>= 1)                        \
        _Pragma("unroll") for (int r = 0; r < 4; ++r)                         \
        if (r < d) ts[r] += ts[r + d];                                        \
    lrow += ts[0];                                                            \
    pf[0] = pack8(st0[0], st0[1], st0[2], st0[3], st0[4], st0[5], st0[6],     \
                  st0[7]);                                                    \
    pf[1] = pack8(st0[8], st0[9], st0[10], st0[11], st0[12], st0[13],         \
                  st0[14], st0[15]);                                          \
    pf[2] = pack8(st1[0], st1[1], st1[2], st1[3], st1[4], st1[5], st1[6],     \
                  st1[7]);                                                    \
    pf[3] = pack8(st1[8], st1[9], st1[10], st1[11], st1[12], st1[13],         \
                  st1[14], st1[15]);                                          \
  }

  for (int ii = 0; ii < NT / 2 - 1; ++ii) {
    // ---- sub-iter A: i = 2*ii (even). QK(i+1) from ODD bank; PV(i) ----------
    {
      bf16x8 pf[4];
      SOFTPACK(pf);
      __builtin_amdgcn_s_setprio(1);
#pragma unroll
      for (int r = 0; r < 16; ++r) { st0[r] = 0.f; st1[r] = 0.f; }
#pragma unroll
      for (int ds = 0; ds < 4; ++ds) {
        st0 = mfma32(kf[8 + ds], qf[ds], st0);
        st1 = mfma32(kf[12 + ds], qf[ds], st1);
      }
#pragma unroll
      for (int kv = 0; kv < 4; ++kv) {
        o0 = mfma32(vf[kv], pf[kv], o0);
        o1 = mfma32(vf[4 + kv], pf[kv], o1);
      }
      __builtin_amdgcn_s_setprio(0);
      // refill odd bank with K(i+3); vf with V(i+1)
#pragma unroll
      for (int ds = 0; ds < 4; ++ds) {
        kf[8 + ds]  = *(const bf16x8*)(kpo + ds * 512);
        kf[12 + ds] = *(const bf16x8*)(kpo + 2048 + ds * 512);
        vf[ds]      = *(const bf16x8*)(vpn + ds * 512);
        vf[4 + ds]  = *(const bf16x8*)(vpn + 2048 + ds * 512);
      }
      kpo += 16384;
      vpn += 8192;
    }
    // ---- sub-iter B: i = 2*ii+1 (odd). QK(i+1) from EVEN bank; PV(i) --------
    {
      bf16x8 pf[4];
      SOFTPACK(pf);
      __builtin_amdgcn_s_setprio(1);
#pragma unroll
      for (int r = 0; r < 16; ++r) { st0[r] = 0.f; st1[r] = 0.f; }
#pragma unroll
      for (int ds = 0; ds < 4; ++ds) {
        st0 = mfma32(kf[ds], qf[ds], st0);
        st1 = mfma32(kf[4 + ds], qf[ds], st1);
      }
#pragma unroll
      for (int kv = 0; kv < 4; ++kv) {
        o0 = mfma32(vf[kv], pf[kv], o0);
        o1 = mfma32(vf[4 + kv], pf[kv], o1);
      }
      __builtin_amdgcn_s_setprio(0);
      // refill even bank with K(i+3) (last one over-reads: allocated ws);
      // vf with V(i+1)
#pragma unroll
      for (int ds = 0; ds < 4; ++ds) {
        kf[ds]     = *(const bf16x8*)(kpe + ds * 512);
        kf[4 + ds] = *(const bf16x8*)(kpe + 2048 + ds * 512);
        vf[ds]     = *(const bf16x8*)(vpn + ds * 512);
        vf[4 + ds] = *(const bf16x8*)(vpn + 2048 + ds * 512);
      }
      kpe += 16384;
      vpn += 8192;
    }
  }

  // tail: i = NT-2 (even): softmax; QK(NT-1) from odd bank + PV; refill vf
  {
    bf16x8 pf[4];
    SOFTPACK(pf);
    __builtin_amdgcn_s_setprio(1);
#pragma unroll
    for (int r = 0; r < 16; ++r) { st0[r] = 0.f; st1[r] = 0.f; }
#pragma unroll
    for (int ds = 0; ds < 4; ++ds) {
      st0 = mfma32(kf[8 + ds], qf[ds], st0);
      st1 = mfma32(kf[12 + ds], qf[ds], st1);
    }
#pragma unroll
    for (int kv = 0; kv < 4; ++kv) {
      o0 = mfma32(vf[kv], pf[kv], o0);
      o1 = mfma32(vf[4 + kv], pf[kv], o1);
    }
    __builtin_amdgcn_s_setprio(0);
#pragma unroll
    for (int ds = 0; ds < 4; ++ds) {
      vf[ds]     = *(const bf16x8*)(vpn + ds * 512);
      vf[4 + ds] = *(const bf16x8*)(vpn + 2048 + ds * 512);
    }
  }
  // tail: i = NT-1: softmax + PV only
  {
    bf16x8 pf[4];
    SOFTPACK(pf);
    __builtin_amdgcn_s_setprio(1);
#pragma unroll
    for (int kv = 0; kv < 4; ++kv) {
      o0 = mfma32(vf[kv], pf[kv], o0);
      o1 = mfma32(vf[4 + kv], pf[kv], o1);
    }
    __builtin_amdgcn_s_setprio(0);
  }
#undef SOFTPACK

  lrow += __shfl_xor(lrow, 32);  // full row sum for this parity

  // ---- merge kv-parities: par 1 -> LDS, par 0 adds + writes -----------------
  if (par == 1) {
#pragma unroll
    for (int g = 0; g < 4; ++g) {
      const int c0 = (2 * g + hi) ^ (lo & 15);  // swizzled 16B chunk
      const int c1 = (8 + 2 * g + hi) ^ (lo & 15);
      f32x4 v0, v1;
#pragma unroll
      for (int r = 0; r < 4; ++r) { v0[r] = o0[g * 4 + r]; v1[r] = o1[g * 4 + r]; }
      *(f32x4*)(&mbuf[wq][lo][c0 * 4]) = v0;
      *(f32x4*)(&mbuf[wq][lo][c1 * 4]) = v1;
    }
    if (hi == 0) lbuf[wq * 32 + lo] = lrow;
  }
  __syncthreads();
  if (par == 0) {
#pragma unroll
    for (int g = 0; g < 4; ++g) {
      const int c0 = (2 * g + hi) ^ (lo & 15);
      const int c1 = (8 + 2 * g + hi) ^ (lo & 15);
      f32x4 v0 = *(const f32x4*)(&mbuf[wq][lo][c0 * 4]);
      f32x4 v1 = *(const f32x4*)(&mbuf[wq][lo][c1 * 4]);
#pragma unroll
      for (int r = 0; r < 4; ++r) { o0[g * 4 + r] += v0[r]; o1[g * 4 + r] += v1[r]; }
    }
    const float inv = 1.0f / (lrow + lbuf[wq * 32 + lo]);
    short* Op = O + base + (size_t)(q0 + lo) * 1024;
#pragma unroll
    for (int g = 0; g < 4; ++g) {
      s16x4 v0, v1;
#pragma unroll
      for (int r = 0; r < 4; ++r) {
        v0[r] = f2bf(o0[g * 4 + r] * inv);
        v1[r] = f2bf(o1[g * 4 + r] * inv);
      }
      *(s16x4*)(Op + 8 * g + 4 * hi) = v0;
      *(s16x4*)(Op + 32 + 8 * g + 4 * hi) = v1;
    }
  }
}

// ---------------------------------------------------------------------------
extern "C" void kernel_launch(void* const* d_in, const int* in_sizes, int n_in,
                              void* d_out, int out_size, void* d_ws, size_t ws_size,
                              hipStream_t stream) {
  const float* x  = (const float*)d_in[0];
  const float* Wq = (const float*)d_in[1];
  const float* bq = (const float*)d_in[2];
  const float* Wk = (const float*)d_in[3];
  const float* bk = (const float*)d_in[4];
  const float* Wv = (const float*)d_in[5];
  const float* bv = (const float*)d_in[6];
  const float* Wo = (const float*)d_in[7];
  const float* bo = (const float*)d_in[8];
  const float* mw = (const float*)d_in[9];
  float* out = (float*)d_out;
  char* ws = (char*)d_ws;
  const size_t MB = (size_t)1 << 20;

  short* xb  = (short*)(ws + 0 * MB);   // 4096x1024 bf16
  short* wqb = (short*)(ws + 8 * MB);
  short* wkb = (short*)(ws + 10 * MB);
  short* wvb = (short*)(ws + 12 * MB);
  short* wob = (short*)(ws + 14 * MB);
  short* qb  = (short*)(ws + 16 * MB);  // scaled Q, row-major
  short* kfb = (short*)(ws + 24 * MB);  // K~ fragment layout (8 MB)
  short* vfb = (short*)(ws + 32 * MB);  // V^T fragment layout (8 MB)
  short* ob  = (short*)(ws + 40 * MB);  // attn out bf16

  cast_all_kernel<<<dim3(512, 8), 256, 0, stream>>>(x, Wq, Wk, Wv, Wo, xb, wqb,
                                                    wkb, wvb, wob);
  gemm_qkv_kernel<<<dim3(8, 32, 3), 512, 0, stream>>>(xb, wqb, wkb, wvb, bq, bk, bv,
                                                      qb, kfb, vfb, mw);
  attn_kernel<<<1024, 256, 0, stream>>>(qb, kfb, vfb, ob);
  gemm_out_kernel<<<dim3(8, 64), 512, 0, stream>>>(ob, wob, bo, out);
}

// Round 15
// 107.974 us; speedup vs baseline: 1.1120x; 1.0572x over previous
//
#include <hip/hip_runtime.h>

// ---------------------------------------------------------------------------
// IncidenceAttention. incidence = (Q·K~^T)*SCALE with K~[d] = K[d] + mw*K[d^32].
// Pipeline: cast -> QKV gemm (4-wave 128^2 tiles, 256 thr, (256,3): grid 768
//           = exactly 3 WG/CU x 256 CU -> ONE full-capacity round, no tail)
//           -> flash attn (2-deep-K, (256,2), setprio clusters; 7-variant
//           plateau ~55us) -> out gemm (64x128, 512 WGs = exactly 2/CU).
// R15: qkv grid-rounding fix. r14's (512,4) qkv = 2 WG/CU -> 768 WGs ran as
// 512 + 256 (half-empty tail round). 4-wave body fits (256,3) without spill.
// ---------------------------------------------------------------------------

typedef __attribute__((ext_vector_type(8))) short short8;
typedef __attribute__((ext_vector_type(4))) short s16x4;
typedef __attribute__((ext_vector_type(4))) float f32x4;
typedef __attribute__((ext_vector_type(16))) float f32x16;
typedef __attribute__((ext_vector_type(8))) __bf16 bf16x8;
typedef __attribute__((ext_vector_type(4))) unsigned uint4v;

__device__ __forceinline__ float exp2fa(float x) {
  return __builtin_amdgcn_exp2f(x);  // v_exp_f32: 2^x
}
__device__ __forceinline__ short f2bf(float f) {
  unsigned u = __builtin_bit_cast(unsigned, f);
  u = u + 0x7fffu + ((u >> 16) & 1u);  // RNE
  return (short)(u >> 16);
}
__device__ __forceinline__ f32x4 mfma16(bf16x8 a, bf16x8 b, f32x4 c) {
  return __builtin_amdgcn_mfma_f32_16x16x32_bf16(a, b, c, 0, 0, 0);
}
__device__ __forceinline__ f32x16 mfma32(bf16x8 a, bf16x8 b, f32x16 c) {
  return __builtin_amdgcn_mfma_f32_32x32x16_bf16(a, b, c, 0, 0, 0);
}
__device__ __forceinline__ void gload_lds16(const void* g, void* l) {
  __builtin_amdgcn_global_load_lds(
      (const __attribute__((address_space(1))) unsigned int*)g,
      (__attribute__((address_space(3))) unsigned int*)l, 16, 0, 0);
}
__device__ __forceinline__ unsigned pkbf(float a, float b) {
  unsigned r;
  asm("v_cvt_pk_bf16_f32 %0, %1, %2" : "=v"(r) : "v"(a), "v"(b));
  return r;
}
__device__ __forceinline__ void plswap(unsigned& a, unsigned& b) {
  asm volatile("v_permlane32_swap_b32 %0, %1" : "+v"(a), "+v"(b));
}
// pack 8 f32 P values into the PV B-operand fragment (m214 T12 pattern).
__device__ __forceinline__ bf16x8 pack8(float x0, float x1, float x2, float x3,
                                        float x4, float x5, float x6, float x7) {
  unsigned a0 = pkbf(x0, x1), a1 = pkbf(x2, x3);
  unsigned a2 = pkbf(x4, x5), a3 = pkbf(x6, x7);
  plswap(a0, a2);
  plswap(a1, a3);
  uint4v u = {a0, a1, a2, a3};
  return __builtin_bit_cast(bf16x8, u);
}

// ---- merged cast: x (4 chunks) + 4 weight matrices, one launch -------------
__global__ void cast_all_kernel(const float* x, const float* w0, const float* w1,
                                const float* w2, const float* w3, short* xo,
                                short* o0, short* o1, short* o2, short* o3) {
  const float* in; short* out;
  const int r = blockIdx.y;
  size_t off;
  if (r < 4) { in = x; out = xo; off = (size_t)r * 131072; }
  else {
    switch (r) {
      case 4: in = w0; out = o0; break;
      case 5: in = w1; out = o1; break;
      case 6: in = w2; out = o2; break;
      default: in = w3; out = o3; break;
    }
    off = 0;
  }
  const size_t i = off + blockIdx.x * 256 + threadIdx.x;
  const float4* p = (const float4*)in;
  float4 a = p[2 * i], b = p[2 * i + 1];
  short8 o;
  o[0] = f2bf(a.x); o[1] = f2bf(a.y); o[2] = f2bf(a.z); o[3] = f2bf(a.w);
  o[4] = f2bf(b.x); o[5] = f2bf(b.y); o[6] = f2bf(b.z); o[7] = f2bf(b.w);
  ((short8*)out)[i] = o;
}

// ---- QKV GEMM: 128x128 tile, BK=64, 4 waves (wave = 64x64), 256 thr --------
// (256,3): 3 WG/CU -> grid 768 = one full-capacity round. VGPR cap ~170.
// EP0: Q scaled bf16 row-major.
// EP1: K folded, fragment layout: per (b,h) [u=s>>5][c=d>>3][lo=s&31][j=d&7]
//      partner col n^32 = acc[mf][nf^2] (nf*16, bit5 = nf&2) - in-wave.
// EP2: V^T fragment layout: per (b,h) [T=s>>6][w2=d>>5][c=(s>>3)&7][dlo=d&31][j=s&7]
constexpr int GK = 1024, GN = 1024;
constexpr float QSCALE = 0.125f * 1.44269504088896340736f;  // SCALE * log2(e)

template <int EP>
__device__ __forceinline__ void gemm_body4(char* lds, const short* __restrict__ A,
                                           const short* __restrict__ W,
                                           const float* __restrict__ bias,
                                           void* __restrict__ C,
                                           const float* __restrict__ mwp) {
  const int tid = threadIdx.x;
  const int l = tid & 63, w = tid >> 6;
  const int wr = w >> 1, wc = w & 1;
  const int m0 = blockIdx.y * 128, n0 = blockIdx.x * 128;

  f32x4 acc[4][4] = {};

  const int rg = l >> 3, c8 = l & 7;
  for (int kb = 0; kb < GK / 64; ++kb) {
    const int k0 = kb * 64;
#pragma unroll
    for (int i = 0; i < 4; ++i) {
      const int ra = i * 32 + w * 8 + rg;
      gload_lds16(A + (size_t)(m0 + ra) * GK + k0 + ((c8 ^ (ra & 7)) * 8),
                  lds + (i * 32 + w * 8) * 128);
      gload_lds16(W + (size_t)(n0 + ra) * GK + k0 + ((c8 ^ (ra & 7)) * 8),
                  lds + 16384 + (i * 32 + w * 8) * 128);
    }
    __syncthreads();
#pragma unroll
    for (int ks = 0; ks < 2; ++ks) {
      bf16x8 af[4], bfr[4];
      const int chunk = ks * 4 + (l >> 4);
#pragma unroll
      for (int mf = 0; mf < 4; ++mf) {
        const int mt = wr * 64 + mf * 16 + (l & 15);
        af[mf] = *(const bf16x8*)(lds + mt * 128 + ((chunk ^ (mt & 7)) * 16));
      }
#pragma unroll
      for (int nf = 0; nf < 4; ++nf) {
        const int nt = wc * 64 + nf * 16 + (l & 15);
        bfr[nf] = *(const bf16x8*)(lds + 16384 + nt * 128 + ((chunk ^ (nt & 7)) * 16));
      }
#pragma unroll
      for (int mf = 0; mf < 4; ++mf)
#pragma unroll
        for (int nf = 0; nf < 4; ++nf)
          acc[mf][nf] = mfma16(af[mf], bfr[nf], acc[mf][nf]);
    }
    __syncthreads();
  }

  const float mwv = (EP == 1) ? mwp[0] : 0.f;
#pragma unroll
  for (int mf = 0; mf < 4; ++mf)
#pragma unroll
    for (int nf = 0; nf < 4; ++nf) {
      const int n = n0 + wc * 64 + nf * 16 + (l & 15);
      const int mb = m0 + wr * 64 + mf * 16 + (l >> 4) * 4;
      if (EP == 1) {  // K~ fragment layout, scalar stores (partner = nf^2)
        const float bv = bias[n], bv2 = bias[n ^ 32];
        const int h = n >> 6, c = (n >> 3) & 7, j = n & 7;
#pragma unroll
        for (int r = 0; r < 4; ++r) {
          const int m = mb + r;
          const int b = m >> 11, s = m & 2047;
          const float v =
              acc[mf][nf][r] + bv + mwv * (acc[mf][nf ^ 2][r] + bv2);
          ((short*)C)[(size_t)(b * 16 + h) * 131072 + (s >> 5) * 2048 + c * 256 +
                      (s & 31) * 8 + j] = f2bf(v);
        }
      } else if (EP == 2) {  // V^T fragment layout, s16x4 stores
        const int h = n >> 6, w2 = (n >> 5) & 1, dlo = n & 31;
        s16x4 v;
#pragma unroll
        for (int r = 0; r < 4; ++r) v[r] = f2bf(acc[mf][nf][r] + bias[n]);
        const int b = mb >> 11, s = mb & 2047;
        *(s16x4*)((short*)C + (size_t)(b * 16 + h) * 131072 + (s >> 6) * 4096 +
                  w2 * 2048 + ((s >> 3) & 7) * 256 + dlo * 8 + (s & 7)) = v;
      } else {  // EP0: Q scaled bf16 row-major
        const float bv = bias[n];
#pragma unroll
        for (int r = 0; r < 4; ++r) {
          const int m = mb + r;
          ((short*)C)[(size_t)m * GN + n] = f2bf((acc[mf][nf][r] + bv) * QSCALE);
        }
      }
    }
}

__global__ __launch_bounds__(256, 3) void gemm_qkv_kernel(
    const short* __restrict__ A, const short* Wq, const short* Wk, const short* Wv,
    const float* bq, const float* bk, const float* bv, short* q, short* kf,
    short* vf, const float* mw) {
  __shared__ __align__(16) char lds[32768];
  if (blockIdx.z == 0) gemm_body4<0>(lds, A, Wq, bq, q, nullptr);
  else if (blockIdx.z == 1) gemm_body4<1>(lds, A, Wk, bk, kf, mw);
  else gemm_body4<2>(lds, A, Wv, bv, vf, nullptr);
}

// ---- out GEMM: 64x128 tile, BK=64, 8 waves (wave = 32x32), 512 WGs ---------
__global__ __launch_bounds__(512, 4) void gemm_out_kernel(const short* __restrict__ A,
                                                          const short* __restrict__ W,
                                                          const float* __restrict__ bias,
                                                          float* __restrict__ C) {
  __shared__ __align__(16) char lds[24576];  // A 8KB | W 16KB
  const int tid = threadIdx.x;
  const int l = tid & 63, w = tid >> 6;
  const int wr = w >> 2, wc = w & 3;  // wave = rows wr*32, cols wc*32
  const int m0 = blockIdx.y * 64, n0 = blockIdx.x * 128;

  f32x4 acc[2][2] = {};

  const int srow = tid >> 3, sc8 = tid & 7, wv = tid >> 6;
  const int sra = srow & 63;  // A staging row (one chunk per thread)
  for (int kb = 0; kb < GK / 64; ++kb) {
    const int k0 = kb * 64;
    gload_lds16(A + (size_t)(m0 + sra) * GK + k0 + ((sc8 ^ (sra & 7)) * 8),
                lds + wv * 1024);
#pragma unroll
    for (int p = 0; p < 2; ++p) {
      const int rw = p * 64 + srow;
      gload_lds16(W + (size_t)(n0 + rw) * GK + k0 + ((sc8 ^ (rw & 7)) * 8),
                  lds + 8192 + p * 8192 + wv * 1024);
    }
    __syncthreads();
#pragma unroll
    for (int ks = 0; ks < 2; ++ks) {
      bf16x8 af[2], bfr[2];
      const int chunk = ks * 4 + (l >> 4);
#pragma unroll
      for (int mf = 0; mf < 2; ++mf) {
        const int mt = wr * 32 + mf * 16 + (l & 15);
        af[mf] = *(const bf16x8*)(lds + mt * 128 + ((chunk ^ (mt & 7)) * 16));
      }
#pragma unroll
      for (int nf = 0; nf < 2; ++nf) {
        const int nt = wc * 32 + nf * 16 + (l & 15);
        bfr[nf] = *(const bf16x8*)(lds + 8192 + nt * 128 + ((chunk ^ (nt & 7)) * 16));
      }
#pragma unroll
      for (int mf = 0; mf < 2; ++mf)
#pragma unroll
        for (int nf = 0; nf < 2; ++nf)
          acc[mf][nf] = mfma16(af[mf], bfr[nf], acc[mf][nf]);
    }
    __syncthreads();
  }

#pragma unroll
  for (int mf = 0; mf < 2; ++mf)
#pragma unroll
    for (int nf = 0; nf < 2; ++nf) {
      const int n = n0 + wc * 32 + nf * 16 + (l & 15);
      const int mb = m0 + wr * 32 + mf * 16 + (l >> 4) * 4;
      const float bv = bias[n];
#pragma unroll
      for (int r = 0; r < 4; ++r)
        C[(size_t)(mb + r) * GN + n] = acc[mf][nf][r] + bv;
    }
}

// ---- flash attention: K 2-deep prefetch, (256,2) so kf[16] fits ------------
// 1024 WGs x 256 thr (4 warps). Warp w: q-sub (w&1), kv-parity (w>>1).
// kf[0..7] = even-local-tile bank, kf[8..15] = odd bank; refilled right after
// their cluster use. vf 1-deep. setprio(1) wraps each MFMA cluster.
__global__ __launch_bounds__(256, 2) void attn_kernel(const short* __restrict__ Q,
                                                      const short* __restrict__ Kf,
                                                      const short* __restrict__ Vf,
                                                      short* __restrict__ O) {
  constexpr int S = 2048;
  constexpr int NT = S / 128;  // local tiles per parity (16)
  __shared__ float mbuf[2][32][64];
  __shared__ float lbuf[64];
  const int tid = threadIdx.x;
  const int l = tid & 63, w = tid >> 6;
  const int lo = l & 31, hi = l >> 5;
  const int wq = w & 1, par = w >> 1;
  const int bid = blockIdx.x;
  const int sub = bid >> 3;
  const int x = sub & 31;
  const int y = (bid & 7) * 4 + (sub >> 5);  // bh index; 4 bh per XCD
  const int b = y >> 4, h = y & 15;
  const int q0 = x * 64 + wq * 32;
  const size_t base = (size_t)b * S * 1024 + h * 64;  // Q/O row-major
  const size_t fbase = (size_t)y * 131072;            // Kf/Vf per-bh block

  // Q fragments: lane holds Q[q0+lo][ds*16 + hi*8 + j]
  bf16x8 qf[4];
  {
    const short* qp = Q + base + (size_t)(q0 + lo) * 1024 + hi * 8;
#pragma unroll
    for (int ds = 0; ds < 4; ++ds) qf[ds] = *(const bf16x8*)(qp + ds * 16);
  }

  const int voff = hi * 256 + lo * 8;  // element offset within a 1KB frag group
  const short* kpe = Kf + fbase + par * 4096 + voff;  // even local tiles
  const short* kpo = kpe + 8192;                      // odd local tiles
  const short* vpn = Vf + fbase + par * 4096 + voff;

  bf16x8 kf[16], vf[8];
#pragma unroll
  for (int ds = 0; ds < 4; ++ds) {
    kf[ds]      = *(const bf16x8*)(kpe + ds * 512);
    kf[4 + ds]  = *(const bf16x8*)(kpe + 2048 + ds * 512);
    kf[8 + ds]  = *(const bf16x8*)(kpo + ds * 512);
    kf[12 + ds] = *(const bf16x8*)(kpo + 2048 + ds * 512);
    vf[ds]      = *(const bf16x8*)(vpn + ds * 512);
    vf[4 + ds]  = *(const bf16x8*)(vpn + 2048 + ds * 512);
  }
  kpe += 16384;  // -> local tile 2
  kpo += 16384;  // -> local tile 3
  vpn += 8192;   // -> local tile 1

  f32x16 o0 = {}, o1 = {};  // O^T: d 0-31 / 32-63 rows, q = lo col
  float lrow = 0.f;         // lane-local partial; cross-32 merged at end

  // prologue: QK(0) from even bank, then refill even bank with K(2)
  f32x16 st0 = {}, st1 = {};
  __builtin_amdgcn_s_setprio(1);
#pragma unroll
  for (int ds = 0; ds < 4; ++ds) {
    st0 = mfma32(kf[ds], qf[ds], st0);
    st1 = mfma32(kf[4 + ds], qf[ds], st1);
  }
  __builtin_amdgcn_s_setprio(0);
#pragma unroll
  for (int ds = 0; ds < 4; ++ds) {
    kf[ds]     = *(const bf16x8*)(kpe + ds * 512);
    kf[4 + ds] = *(const bf16x8*)(kpe + 2048 + ds * 512);
  }
  kpe += 16384;

  // softmax + pack macro body (operates on st0/st1 -> pf, updates lrow)
#define SOFTPACK(pf)                                                          \
  {                                                                           \
    _Pragma("unroll") for (int r = 0; r < 16; ++r) st0[r] = exp2fa(st0[r]);   \
    _Pragma("unroll") for (int r = 0; r < 16; ++r) st1[r] = exp2fa(st1[r]);   \
    float ts[8];                                                              \
    _Pragma("unroll") for (int r = 0; r < 8; ++r) ts[r] =                     \
        (st0[r] + st0[r + 8]) + (st1[r] + st1[r + 8]);                        \
    _Pragma("unroll") for (int d = 4; d >= 1; d >>= 1)                        \
        _Pragma("unroll") for (int r = 0; r < 4; ++r)                         \
        if (r < d) ts[r] += ts[r + d];                                        \
    lrow += ts[0];                                                            \
    pf[0] = pack8(st0[0], st0[1], st0[2], st0[3], st0[4], st0[5], st0[6],     \
                  st0[7]);                                                    \
    pf[1] = pack8(st0[8], st0[9], st0[10], st0[11], st0[12], st0[13],         \
                  st0[14], st0[15]);                                          \
    pf[2] = pack8(st1[0], st1[1], st1[2], st1[3], st1[4], st1[5], st1[6],     \
                  st1[7]);                                                    \
    pf[3] = pack8(st1[8], st1[9], st1[10], st1[11], st1[12], st1[13],         \
                  st1[14], st1[15]);                                          \
  }

  for (int ii = 0; ii < NT / 2 - 1; ++ii) {
    // ---- sub-iter A: i = 2*ii (even). QK(i+1) from ODD bank; PV(i) ----------
    {
      bf16x8 pf[4];
      SOFTPACK(pf);
      __builtin_amdgcn_s_setprio(1);
#pragma unroll
      for (int r = 0; r < 16; ++r) { st0[r] = 0.f; st1[r] = 0.f; }
#pragma unroll
      for (int ds = 0; ds < 4; ++ds) {
        st0 = mfma32(kf[8 + ds], qf[ds], st0);
        st1 = mfma32(kf[12 + ds], qf[ds], st1);
      }
#pragma unroll
      for (int kv = 0; kv < 4; ++kv) {
        o0 = mfma32(vf[kv], pf[kv], o0);
        o1 = mfma32(vf[4 + kv], pf[kv], o1);
      }
      __builtin_amdgcn_s_setprio(0);
      // refill odd bank with K(i+3); vf with V(i+1)
#pragma unroll
      for (int ds = 0; ds < 4; ++ds) {
        kf[8 + ds]  = *(const bf16x8*)(kpo + ds * 512);
        kf[12 + ds] = *(const bf16x8*)(kpo + 2048 + ds * 512);
        vf[ds]      = *(const bf16x8*)(vpn + ds * 512);
        vf[4 + ds]  = *(const bf16x8*)(vpn + 2048 + ds * 512);
      }
      kpo += 16384;
      vpn += 8192;
    }
    // ---- sub-iter B: i = 2*ii+1 (odd). QK(i+1) from EVEN bank; PV(i) --------
    {
      bf16x8 pf[4];
      SOFTPACK(pf);
      __builtin_amdgcn_s_setprio(1);
#pragma unroll
      for (int r = 0; r < 16; ++r) { st0[r] = 0.f; st1[r] = 0.f; }
#pragma unroll
      for (int ds = 0; ds < 4; ++ds) {
        st0 = mfma32(kf[ds], qf[ds], st0);
        st1 = mfma32(kf[4 + ds], qf[ds], st1);
      }
#pragma unroll
      for (int kv = 0; kv < 4; ++kv) {
        o0 = mfma32(vf[kv], pf[kv], o0);
        o1 = mfma32(vf[4 + kv], pf[kv], o1);
      }
      __builtin_amdgcn_s_setprio(0);
      // refill even bank with K(i+3) (last one over-reads: allocated ws);
      // vf with V(i+1)
#pragma unroll
      for (int ds = 0; ds < 4; ++ds) {
        kf[ds]     = *(const bf16x8*)(kpe + ds * 512);
        kf[4 + ds] = *(const bf16x8*)(kpe + 2048 + ds * 512);
        vf[ds]     = *(const bf16x8*)(vpn + ds * 512);
        vf[4 + ds] = *(const bf16x8*)(vpn + 2048 + ds * 512);
      }
      kpe += 16384;
      vpn += 8192;
    }
  }

  // tail: i = NT-2 (even): softmax; QK(NT-1) from odd bank + PV; refill vf
  {
    bf16x8 pf[4];
    SOFTPACK(pf);
    __builtin_amdgcn_s_setprio(1);
#pragma unroll
    for (int r = 0; r < 16; ++r) { st0[r] = 0.f; st1[r] = 0.f; }
#pragma unroll
    for (int ds = 0; ds < 4; ++ds) {
      st0 = mfma32(kf[8 + ds], qf[ds], st0);
      st1 = mfma32(kf[12 + ds], qf[ds], st1);
    }
#pragma unroll
    for (int kv = 0; kv < 4; ++kv) {
      o0 = mfma32(vf[kv], pf[kv], o0);
      o1 = mfma32(vf[4 + kv], pf[kv], o1);
    }
    __builtin_amdgcn_s_setprio(0);
#pragma unroll
    for (int ds = 0; ds < 4; ++ds) {
      vf[ds]     = *(const bf16x8*)(vpn + ds * 512);
      vf[4 + ds] = *(const bf16x8*)(vpn + 2048 + ds * 512);
    }
  }
  // tail: i = NT-1: softmax + PV only
  {
    bf16x8 pf[4];
    SOFTPACK(pf);
    __builtin_amdgcn_s_setprio(1);
#pragma unroll
    for (int kv = 0; kv < 4; ++kv) {
      o0 = mfma32(vf[kv], pf[kv], o0);
      o1 = mfma32(vf[4 + kv], pf[kv], o1);
    }
    __builtin_amdgcn_s_setprio(0);
  }
#undef SOFTPACK

  lrow += __shfl_xor(lrow, 32);  // full row sum for this parity

  // ---- merge kv-parities: par 1 -> LDS, par 0 adds + writes -----------------
  if (par == 1) {
#pragma unroll
    for (int g = 0; g < 4; ++g) {
      const int c0 = (2 * g + hi) ^ (lo & 15);  // swizzled 16B chunk
      const int c1 = (8 + 2 * g + hi) ^ (lo & 15);
      f32x4 v0, v1;
#pragma unroll
      for (int r = 0; r < 4; ++r) { v0[r] = o0[g * 4 + r]; v1[r] = o1[g * 4 + r]; }
      *(f32x4*)(&mbuf[wq][lo][c0 * 4]) = v0;
      *(f32x4*)(&mbuf[wq][lo][c1 * 4]) = v1;
    }
    if (hi == 0) lbuf[wq * 32 + lo] = lrow;
  }
  __syncthreads();
  if (par == 0) {
#pragma unroll
    for (int g = 0; g < 4; ++g) {
      const int c0 = (2 * g + hi) ^ (lo & 15);
      const int c1 = (8 + 2 * g + hi) ^ (lo & 15);
      f32x4 v0 = *(const f32x4*)(&mbuf[wq][lo][c0 * 4]);
      f32x4 v1 = *(const f32x4*)(&mbuf[wq][lo][c1 * 4]);
#pragma unroll
      for (int r = 0; r < 4; ++r) { o0[g * 4 + r] += v0[r]; o1[g * 4 + r] += v1[r]; }
    }
    const float inv = 1.0f / (lrow + lbuf[wq * 32 + lo]);
    short* Op = O + base + (size_t)(q0 + lo) * 1024;
#pragma unroll
    for (int g = 0; g < 4; ++g) {
      s16x4 v0, v1;
#pragma unroll
      for (int r = 0; r < 4; ++r) {
        v0[r] = f2bf(o0[g * 4 + r] * inv);
        v1[r] = f2bf(o1[g * 4 + r] * inv);
      }
      *(s16x4*)(Op + 8 * g + 4 * hi) = v0;
      *(s16x4*)(Op + 32 + 8 * g + 4 * hi) = v1;
    }
  }
}

// ---------------------------------------------------------------------------
extern "C" void kernel_launch(void* const* d_in, const int* in_sizes, int n_in,
                              void* d_out, int out_size, void* d_ws, size_t ws_size,
                              hipStream_t stream) {
  const float* x  = (const float*)d_in[0];
  const float* Wq = (const float*)d_in[1];
  const float* bq = (const float*)d_in[2];
  const float* Wk = (const float*)d_in[3];
  const float* bk = (const float*)d_in[4];
  const float* Wv = (const float*)d_in[5];
  const float* bv = (const float*)d_in[6];
  const float* Wo = (const float*)d_in[7];
  const float* bo = (const float*)d_in[8];
  const float* mw = (const float*)d_in[9];
  float* out = (float*)d_out;
  char* ws = (char*)d_ws;
  const size_t MB = (size_t)1 << 20;

  short* xb  = (short*)(ws + 0 * MB);   // 4096x1024 bf16
  short* wqb = (short*)(ws + 8 * MB);
  short* wkb = (short*)(ws + 10 * MB);
  short* wvb = (short*)(ws + 12 * MB);
  short* wob = (short*)(ws + 14 * MB);
  short* qb  = (short*)(ws + 16 * MB);  // scaled Q, row-major
  short* kfb = (short*)(ws + 24 * MB);  // K~ fragment layout (8 MB)
  short* vfb = (short*)(ws + 32 * MB);  // V^T fragment layout (8 MB)
  short* ob  = (short*)(ws + 40 * MB);  // attn out bf16

  cast_all_kernel<<<dim3(512, 8), 256, 0, stream>>>(x, Wq, Wk, Wv, Wo, xb, wqb,
                                                    wkb, wvb, wob);
  gemm_qkv_kernel<<<dim3(8, 32, 3), 256, 0, stream>>>(xb, wqb, wkb, wvb, bq, bk, bv,
                                                      qb, kfb, vfb, mw);
  attn_kernel<<<1024, 256, 0, stream>>>(qb, kfb, vfb, ob);
  gemm_out_kernel<<<dim3(8, 64), 512, 0, stream>>>(ob, wob, bo, out);
}